// Round 3
// baseline (1594.564 us; speedup 1.0000x reference)
//
#include <hip/hip_runtime.h>
#include <math.h>

#define IMG_H 512
#define IMG_W 512
#define NPLANE 48            // 16 batches * 3 channels
#define SEG 64               // output rows per wave-task
#define NXT 8                // 512/64 column tiles
#define NSEG 8               // 512/64 row segments
#define NTASK (NPLANE*NXT*NSEG)   // 3072 waves
#define NPIX 12582912.0      // 16*3*512*512

struct GaussW { float w[11]; };

__global__ void ssim_zero_kernel(double* acc) {
    if (threadIdx.x == 0) acc[0] = 0.0;
}

__global__ __launch_bounds__(256, 3)
void ssim_main_kernel(const float* __restrict__ pred,
                      const float* __restrict__ targ,
                      double* __restrict__ acc,
                      GaussW gw) {
    const int wid  = (blockIdx.x << 2) + (threadIdx.x >> 6);
    const int lane = threadIdx.x & 63;
    const int xt   = wid & 7;          // adjacent waves share x-halo in L1/L2
    const int yseg = (wid >> 3) & 7;
    const int pl   = wid >> 6;
    const int x    = (xt << 6) + lane;
    const int y0   = yseg << 6;

    const float* __restrict__ pb = pred + (size_t)pl * (IMG_H * IMG_W);
    const float* __restrict__ tb = targ + (size_t)pl * (IMG_H * IMG_W);

    // Per-lane clamped tap columns + masked weights (hoisted out of all rows).
    // Out-of-image taps: weight 0, address clamped in-range (safe, value ignored).
    int   cx[11];
    float wv[11];
#pragma unroll
    for (int k = 0; k < 11; ++k) {
        int c = x + k - 5;
        bool v = (unsigned)c < (unsigned)IMG_W;
        cx[k] = v ? c : (c < 0 ? 0 : IMG_W - 1);
        wv[k] = v ? gw.w[k] : 0.f;
    }

    // Register ring: 11 rows of horizontal-conv results for the 5 fields.
    float rmx[11], rmy[11], rxx[11], ryy[11], rxy[11];

    auto hrow = [&](int y, float& mx, float& my, float& xx, float& yy, float& xy) {
        if ((unsigned)y >= (unsigned)IMG_H) { mx = my = xx = yy = xy = 0.f; return; }
        const float* __restrict__ pr = pb + y * IMG_W;
        const float* __restrict__ tr = tb + y * IMG_W;
        float amx = 0.f, amy = 0.f, axx = 0.f, ayy = 0.f, axy = 0.f;
#pragma unroll
        for (int k = 0; k < 11; ++k) {
            float p  = pr[cx[k]];
            float t  = tr[cx[k]];
            float wp = wv[k] * p;
            float wt = wv[k] * t;
            amx += wp;
            amy += wt;
            axx = fmaf(wp, p, axx);
            ayy = fmaf(wt, t, ayy);
            axy = fmaf(wp, t, axy);
        }
        mx = amx; my = amy; xx = axx; yy = ayy; xy = axy;
    };

    // Prologue: fill ring slots 0..9 with hconv rows y0-5 .. y0+4
#pragma unroll
    for (int s = 0; s < 10; ++s)
        hrow(y0 - 5 + s, rmx[s], rmy[s], rxx[s], ryy[s], rxy[s]);

    const float C1 = 0.0001f;   // 0.01^2
    const float C2 = 0.0009f;   // 0.03^2
    float sum = 0.f;

    // Main: 66 steps (6 x 11 so ring indices stay compile-time), last 2 masked.
#pragma unroll 1
    for (int c = 0; c < 6; ++c) {
#pragma unroll
        for (int jj = 0; jj < 11; ++jj) {
            const int j    = c * 11 + jj;        // output row offset within segment
            const int snew = (jj + 10) % 11;     // ring slot for hconv row j+10
            hrow(y0 + 5 + j, rmx[snew], rmy[snew], rxx[snew], ryy[snew], rxy[snew]);

            float mx = 0.f, my = 0.f, xx = 0.f, yy = 0.f, xy = 0.f;
#pragma unroll
            for (int k = 0; k < 11; ++k) {
                const int s = (jj + k) % 11;     // compile-time after unroll
                const float wk = gw.w[k];        // SGPR operand
                mx = fmaf(wk, rmx[s], mx);
                my = fmaf(wk, rmy[s], my);
                xx = fmaf(wk, rxx[s], xx);
                yy = fmaf(wk, ryy[s], yy);
                xy = fmaf(wk, rxy[s], xy);
            }
            const float mx2  = mx * mx, my2 = my * my;
            const float mxy2 = 2.f * (mx * my);
            const float sx   = xx - mx2, sy = yy - my2;
            const float sxy2 = 2.f * xy - mxy2;
            const float num  = (mxy2 + C1) * (sxy2 + C2);
            const float den  = (mx2 + my2 + C1) * (sx + sy + C2);
            const float ssim = __fdividef(num, den);
            sum += (j < 64) ? ssim : 0.f;
        }
    }

    // Wave tree-reduce, one f64 atomic per wave (3072 total).
#pragma unroll
    for (int m = 32; m > 0; m >>= 1) sum += __shfl_xor(sum, m);
    if (lane == 0) atomicAdd(acc, (double)sum);
}

__global__ void ssim_fin_kernel(const double* __restrict__ acc, float* __restrict__ out) {
    out[0] = (float)(1.0 - acc[0] / NPIX);
}

extern "C" void kernel_launch(void* const* d_in, const int* in_sizes, int n_in,
                              void* d_out, int out_size, void* d_ws, size_t ws_size,
                              hipStream_t stream) {
    const float* pred = (const float*)d_in[0];
    const float* targ = (const float*)d_in[1];
    float* out  = (float*)d_out;
    double* acc = (double*)d_ws;

    // Gaussian window (matches reference: exp(-(i-5)^2 / (2*1.5^2)), normalized)
    GaussW gw;
    double g[11], s = 0.0;
    for (int i = 0; i < 11; ++i) { double d = i - 5; g[i] = exp(-(d * d) / 4.5); s += g[i]; }
    for (int i = 0; i < 11; ++i) gw.w[i] = (float)(g[i] / s);

    ssim_zero_kernel<<<1, 64, 0, stream>>>(acc);
    ssim_main_kernel<<<NTASK / 4, 256, 0, stream>>>(pred, targ, acc, gw);
    ssim_fin_kernel<<<1, 1, 0, stream>>>(acc, out);
}

// Round 5
// 518.314 us; speedup vs baseline: 3.0764x; 3.0764x over previous
//
#include <hip/hip_runtime.h>
#include <math.h>

#define IMG_H 512
#define IMG_W 512
#define NPLANE 48                 // 16 batches * 3 channels
#define NXT 8                     // 512/64 column tiles
#define NSEG 8                    // 512/64 row segments
#define NTASK (NPLANE*NXT*NSEG)   // 3072 waves
#define NPIX 12582912.0           // 16*3*512*512

struct GaussW { float w[11]; };

__global__ void ssim_zero_kernel(double* acc) {
    if (threadIdx.x == 0) acc[0] = 0.0;
}

// One wave owns a 64-col x 64-row tile of one (b,c) plane.
// hconv once per (row,lane) into an 11-deep register ring of 5 fields;
// ring indices are LITERAL via macro-expanded phases (rule #20: no
// runtime-indexed arrays -> nothing in scratch).
__global__ __launch_bounds__(256, 3)
void ssim_main_kernel(const float* __restrict__ pred,
                      const float* __restrict__ targ,
                      double* __restrict__ acc,
                      GaussW gw) {
    const int wid  = (blockIdx.x << 2) + (threadIdx.x >> 6);
    const int lane = threadIdx.x & 63;
    const int xt   = wid & 7;          // adjacent waves share x-halo in L1/L2
    const int yseg = (wid >> 3) & 7;
    const int pl   = wid >> 6;
    const int x    = (xt << 6) + lane;
    const int y0   = yseg << 6;

    const float* __restrict__ pb = pred + (size_t)pl * (IMG_H * IMG_W);
    const float* __restrict__ tb = targ + (size_t)pl * (IMG_H * IMG_W);

    // Per-lane clamped tap columns + masked weights (hoisted out of all rows).
    int   cx[11];
    float wv[11];
#pragma unroll
    for (int k = 0; k < 11; ++k) {
        int c = x + k - 5;
        bool v = (unsigned)c < (unsigned)IMG_W;
        cx[k] = v ? c : (c < 0 ? 0 : IMG_W - 1);
        wv[k] = v ? gw.w[k] : 0.f;
    }

    // Register ring: 11 rows of horizontal-conv results for the 5 fields.
    // Every access below uses a compile-time-constant index.
    float rmx[11], rmy[11], rxx[11], ryy[11], rxy[11];

// Horizontal 11-tap conv of row YV into ring slot SLOT (SLOT is a literal).
#define HROW(YV, SLOT) do {                                                  \
    const int y_ = (YV);                                                     \
    float amx = 0.f, amy = 0.f, axx = 0.f, ayy = 0.f, axy = 0.f;             \
    if ((unsigned)y_ < (unsigned)IMG_H) {  /* wave-uniform branch */         \
        const float* __restrict__ pr = pb + y_ * IMG_W;                      \
        const float* __restrict__ tr = tb + y_ * IMG_W;                      \
        _Pragma("unroll")                                                    \
        for (int k = 0; k < 11; ++k) {                                       \
            float p  = pr[cx[k]];                                            \
            float t  = tr[cx[k]];                                            \
            float wp = wv[k] * p;                                            \
            float wt = wv[k] * t;                                            \
            amx += wp; amy += wt;                                            \
            axx = fmaf(wp, p, axx);                                          \
            ayy = fmaf(wt, t, ayy);                                          \
            axy = fmaf(wp, t, axy);                                          \
        }                                                                    \
    }                                                                        \
    rmx[SLOT] = amx; rmy[SLOT] = amy;                                        \
    rxx[SLOT] = axx; ryy[SLOT] = ayy; rxy[SLOT] = axy;                       \
} while (0)

    // Prologue: slots 0..9 = hconv of rows y0-5 .. y0+4 (literal slots).
    HROW(y0 - 5, 0); HROW(y0 - 4, 1); HROW(y0 - 3, 2); HROW(y0 - 2, 3);
    HROW(y0 - 1, 4); HROW(y0 + 0, 5); HROW(y0 + 1, 6); HROW(y0 + 2, 7);
    HROW(y0 + 3, 8); HROW(y0 + 4, 9);

    const float C1 = 0.0001f;   // 0.01^2
    const float C2 = 0.0009f;   // 0.03^2
    float sum = 0.f;

// One output row at phase JJ (JJ is a LITERAL 0..10): hconv row j+10 into
// slot (JJ+10)%11, vertical conv over slots (JJ+k)%11, SSIM, accumulate.
#define PHASE(JJ) do {                                                       \
    const int j_ = c * 11 + (JJ);                                            \
    HROW(y0 + 5 + j_, (((JJ) + 10) % 11));                                   \
    float mx = 0.f, my = 0.f, xx = 0.f, yy = 0.f, xy = 0.f;                  \
    _Pragma("unroll")                                                        \
    for (int k = 0; k < 11; ++k) {                                           \
        const int s_ = ((JJ) + k) % 11;   /* constant after unroll */        \
        const float wk = gw.w[k];         /* SGPR operand */                 \
        mx = fmaf(wk, rmx[s_], mx);                                          \
        my = fmaf(wk, rmy[s_], my);                                          \
        xx = fmaf(wk, rxx[s_], xx);                                          \
        yy = fmaf(wk, ryy[s_], yy);                                          \
        xy = fmaf(wk, rxy[s_], xy);                                          \
    }                                                                        \
    const float mx2  = mx * mx, my2 = my * my;                               \
    const float mxy2 = 2.f * (mx * my);                                      \
    const float sx   = xx - mx2, sy = yy - my2;                              \
    const float sxy2 = 2.f * xy - mxy2;                                      \
    const float num  = (mxy2 + C1) * (sxy2 + C2);                            \
    const float den  = (mx2 + my2 + C1) * (sx + sy + C2);                    \
    sum += (j_ < 64) ? __fdividef(num, den) : 0.f;                           \
} while (0)

    // 66 steps = 6 chunks x 11 literal phases; last 2 steps masked (j>=64).
#pragma unroll 1
    for (int c = 0; c < 6; ++c) {
        PHASE(0); PHASE(1); PHASE(2); PHASE(3); PHASE(4); PHASE(5);
        PHASE(6); PHASE(7); PHASE(8); PHASE(9); PHASE(10);
    }

#undef PHASE
#undef HROW

    // Wave tree-reduce, one f64 atomic per wave (3072 total).
#pragma unroll
    for (int m = 32; m > 0; m >>= 1) sum += __shfl_xor(sum, m);
    if (lane == 0) atomicAdd(acc, (double)sum);
}

__global__ void ssim_fin_kernel(const double* __restrict__ acc, float* __restrict__ out) {
    out[0] = (float)(1.0 - acc[0] / NPIX);
}

extern "C" void kernel_launch(void* const* d_in, const int* in_sizes, int n_in,
                              void* d_out, int out_size, void* d_ws, size_t ws_size,
                              hipStream_t stream) {
    const float* pred = (const float*)d_in[0];
    const float* targ = (const float*)d_in[1];
    float* out  = (float*)d_out;
    double* acc = (double*)d_ws;

    // Gaussian window (matches reference: exp(-(i-5)^2 / (2*1.5^2)), normalized)
    GaussW gw;
    double g[11], s = 0.0;
    for (int i = 0; i < 11; ++i) { double d = i - 5; g[i] = exp(-(d * d) / 4.5); s += g[i]; }
    for (int i = 0; i < 11; ++i) gw.w[i] = (float)(g[i] / s);

    ssim_zero_kernel<<<1, 64, 0, stream>>>(acc);
    ssim_main_kernel<<<NTASK / 4, 256, 0, stream>>>(pred, targ, acc, gw);
    ssim_fin_kernel<<<1, 1, 0, stream>>>(acc, out);
}